// Round 1
// baseline (1392.786 us; speedup 1.0000x reference)
//
#include <hip/hip_runtime.h>
#include <math.h>

#define BB 8
#define NN 784
#define CC 768
#define HH 16
#define DD 48
#define SGRID 28
#define MROWS (BB*NN)                 // 6272
#define SCALE 0.14433756729740643f    // 48^-0.5

// d_out layout (floats): out [B,N,C] | attn [B,H,N,N] | v [B,H,N,D]
#define ATTN_OFF ((size_t)BB*NN*CC)                  // 4816896
#define V_OFF (ATTN_OFF + (size_t)BB*HH*NN*NN)       // 83492864

// workspace layout (floats)
#define WS_Q   ((size_t)0)
#define WS_K   ((size_t)BB*HH*NN*DD)                 // 4816896
#define WS_POS ((size_t)2*BB*HH*NN*DD)               // 9633792
#define WS_O   (WS_POS + (size_t)HH*NN*NN)           // 19468288

// ---------------------------------------------------------------------------
// K1: fused QKV projection. A = x [6272,768] row-major, W[o,c] row-major (NT).
// grid (98, 36): y/12 selects weight, y%12 selects 64-col slab.
// q,k -> ws in [B,H,N,D]; v -> d_out v-section in [B,H,N,D].
// ---------------------------------------------------------------------------
__global__ __launch_bounds__(256) void qkv_kernel(
    const float* __restrict__ x, const float* __restrict__ Wq,
    const float* __restrict__ Wk, const float* __restrict__ Wv,
    float* __restrict__ qo, float* __restrict__ ko, float* __restrict__ vo)
{
    const int wsel = blockIdx.y / 12;
    const int col0 = (blockIdx.y % 12) * 64;
    const int row0 = blockIdx.x * 64;
    const float* W = (wsel == 0) ? Wq : (wsel == 1) ? Wk : Wv;
    float* dst = (wsel == 0) ? qo : (wsel == 1) ? ko : vo;

    __shared__ float As[16][68];   // As[k][m], pitch 68 keeps float4 alignment
    __shared__ float Bs[16][68];
    const int t = threadIdx.x, tx = t & 15, ty = t >> 4;
    float acc[4][4] = {};

    for (int kt = 0; kt < CC; kt += 16) {
#pragma unroll
        for (int i = 0; i < 4; i++) {
            int m = ty + 16 * i;
            As[tx][m] = x[(size_t)(row0 + m) * CC + kt + tx];
            Bs[tx][m] = W[(size_t)(col0 + m) * CC + kt + tx];
        }
        __syncthreads();
#pragma unroll
        for (int kk = 0; kk < 16; kk++) {
            float4 av = *(const float4*)&As[kk][ty * 4];
            float4 bv = *(const float4*)&Bs[kk][tx * 4];
            float a4[4] = {av.x, av.y, av.z, av.w};
            float b4[4] = {bv.x, bv.y, bv.z, bv.w};
#pragma unroll
            for (int i = 0; i < 4; i++)
#pragma unroll
                for (int j = 0; j < 4; j++)
                    acc[i][j] = fmaf(a4[i], b4[j], acc[i][j]);
        }
        __syncthreads();
    }
#pragma unroll
    for (int i = 0; i < 4; i++) {
        int row = row0 + ty * 4 + i;
        int b = row / NN, n = row % NN;
#pragma unroll
        for (int j = 0; j < 4; j++) {
            int o = col0 + tx * 4 + j;
            int h = o / DD, d = o % DD;
            dst[(((size_t)b * HH + h) * NN + n) * DD + d] = acc[i][j];
        }
    }
}

// ---------------------------------------------------------------------------
// K2: positional softmax -> ws_pos [H,N,N]. One block per (h,n) row.
// ---------------------------------------------------------------------------
__global__ __launch_bounds__(256) void pos_kernel(
    const float* __restrict__ W_pos, const float* __restrict__ b_pos,
    float* __restrict__ pos)
{
    const int bid = blockIdx.x;              // h*784 + n
    const int h = bid / NN, n = bid % NN;
    const float w0 = W_pos[h * 3], w1 = W_pos[h * 3 + 1], w2 = W_pos[h * 3 + 2];
    const float bp = b_pos[h];
    const int nx = n % SGRID, ny = n / SGRID;

    __shared__ float buf[NN];
    __shared__ float red[8];
    const int t = threadIdx.x;

    float lmax = -1e30f;
    for (int m = t; m < NN; m += 256) {
        float dx = (float)(m % SGRID - nx);
        float dy = (float)(m / SGRID - ny);
        float v = fmaf(w2, dx * dx + dy * dy, fmaf(w0, dx, fmaf(w1, dy, bp)));
        buf[m] = v;
        lmax = fmaxf(lmax, v);
    }
    for (int off = 32; off; off >>= 1) lmax = fmaxf(lmax, __shfl_xor(lmax, off, 64));
    if ((t & 63) == 0) red[t >> 6] = lmax;
    __syncthreads();
    float rmax = fmaxf(fmaxf(red[0], red[1]), fmaxf(red[2], red[3]));
    float lsum = 0.f;
    for (int m = t; m < NN; m += 256) {
        float e = __expf(buf[m] - rmax);
        buf[m] = e;
        lsum += e;
    }
    for (int off = 32; off; off >>= 1) lsum += __shfl_xor(lsum, off, 64);
    if ((t & 63) == 0) red[4 + (t >> 6)] = lsum;
    __syncthreads();
    float inv = 1.f / (red[4] + red[5] + red[6] + red[7]);
    for (int m = t; m < NN; m += 256)
        pos[(size_t)bid * NN + m] = buf[m] * inv;
}

// ---------------------------------------------------------------------------
// K3: raw scores S = q k^T * SCALE -> attn region (pre-softmax).
// grid (13, 13, 128): z = b*16+h. K = 48 (3 k-tiles of 16).
// ---------------------------------------------------------------------------
__global__ __launch_bounds__(256) void score_kernel(
    const float* __restrict__ q, const float* __restrict__ k,
    float* __restrict__ attn)
{
    const int bh = blockIdx.z;
    const int row0 = blockIdx.x * 64, col0 = blockIdx.y * 64;
    const float* qb = q + (size_t)bh * NN * DD;
    const float* kb = k + (size_t)bh * NN * DD;
    float* ab = attn + (size_t)bh * NN * NN;

    __shared__ float As[16][68];
    __shared__ float Bs[16][68];
    const int t = threadIdx.x, tx = t & 15, ty = t >> 4;
    float acc[4][4] = {};

    for (int kt = 0; kt < DD; kt += 16) {
#pragma unroll
        for (int i = 0; i < 4; i++) {
            int m = ty + 16 * i;
            int rA = row0 + m, rB = col0 + m;
            As[tx][m] = (rA < NN) ? qb[(size_t)rA * DD + kt + tx] : 0.f;
            Bs[tx][m] = (rB < NN) ? kb[(size_t)rB * DD + kt + tx] : 0.f;
        }
        __syncthreads();
#pragma unroll
        for (int kk = 0; kk < 16; kk++) {
            float4 av = *(const float4*)&As[kk][ty * 4];
            float4 bv = *(const float4*)&Bs[kk][tx * 4];
            float a4[4] = {av.x, av.y, av.z, av.w};
            float b4[4] = {bv.x, bv.y, bv.z, bv.w};
#pragma unroll
            for (int i = 0; i < 4; i++)
#pragma unroll
                for (int j = 0; j < 4; j++)
                    acc[i][j] = fmaf(a4[i], b4[j], acc[i][j]);
        }
        __syncthreads();
    }
#pragma unroll
    for (int i = 0; i < 4; i++) {
        int r = row0 + ty * 4 + i;
        if (r >= NN) continue;
#pragma unroll
        for (int j = 0; j < 4; j++) {
            int c = col0 + tx * 4 + j;
            if (c < NN) ab[(size_t)r * NN + c] = acc[i][j] * SCALE;
        }
    }
}

// ---------------------------------------------------------------------------
// K4: in-place per-row softmax + gated blend with pos + renormalize.
// One block per attn row; grid = B*H*N = 100352.
// ---------------------------------------------------------------------------
__global__ __launch_bounds__(256) void blend_kernel(
    const float* __restrict__ pos, const float* __restrict__ gating,
    float* __restrict__ attn)
{
    const int row = blockIdx.x;              // (b*16+h)*784 + n
    const int n = row % NN;
    const int h = (row / NN) % HH;
    const float g = 1.f / (1.f + __expf(-gating[h]));
    float* arow = attn + (size_t)row * NN;
    const float* prow = pos + ((size_t)h * NN + n) * NN;

    __shared__ float buf[NN];
    __shared__ float red[12];
    const int t = threadIdx.x;

    float lmax = -1e30f;
    for (int m = t; m < NN; m += 256) {
        float v = arow[m];
        buf[m] = v;
        lmax = fmaxf(lmax, v);
    }
    for (int off = 32; off; off >>= 1) lmax = fmaxf(lmax, __shfl_xor(lmax, off, 64));
    if ((t & 63) == 0) red[t >> 6] = lmax;
    __syncthreads();
    float rmax = fmaxf(fmaxf(red[0], red[1]), fmaxf(red[2], red[3]));
    float lsum = 0.f;
    for (int m = t; m < NN; m += 256) {
        float e = __expf(buf[m] - rmax);
        buf[m] = e;
        lsum += e;
    }
    for (int off = 32; off; off >>= 1) lsum += __shfl_xor(lsum, off, 64);
    if ((t & 63) == 0) red[4 + (t >> 6)] = lsum;
    __syncthreads();
    float inv = 1.f / (red[4] + red[5] + red[6] + red[7]);
    float lsa = 0.f;
    for (int m = t; m < NN; m += 256) {
        float a = (1.f - g) * buf[m] * inv + g * prow[m];
        buf[m] = a;
        lsa += a;
    }
    for (int off = 32; off; off >>= 1) lsa += __shfl_xor(lsa, off, 64);
    if ((t & 63) == 0) red[8 + (t >> 6)] = lsa;
    __syncthreads();
    float inv2 = 1.f / (red[8] + red[9] + red[10] + red[11]);
    for (int m = t; m < NN; m += 256) arow[m] = buf[m] * inv2;
}

// ---------------------------------------------------------------------------
// K5: out_heads = attn @ v -> ws_o in [B,N,C] layout (c = h*48+d).
// grid (13, 1, 128). NN GEMM, K = 784 (49 tiles of 16), Ncols = 48.
// ---------------------------------------------------------------------------
__global__ __launch_bounds__(256) void pv_kernel(
    const float* __restrict__ attn, const float* __restrict__ v,
    float* __restrict__ ws_o)
{
    const int bh = blockIdx.z;
    const int b = bh >> 4, h = bh & 15;
    const int row0 = blockIdx.x * 64;
    const float* ab = attn + (size_t)bh * NN * NN;
    const float* vb = v + (size_t)bh * NN * DD;

    __shared__ float As[16][68];   // As[k][m]
    __shared__ float Bs[16][DD];   // v tile [k][d]
    const int t = threadIdx.x, tx = t & 15, ty = t >> 4;
    float acc[4][3] = {};

    for (int kt = 0; kt < NN; kt += 16) {
#pragma unroll
        for (int i = 0; i < 4; i++) {
            int m = ty + 16 * i;
            int r = row0 + m;
            As[tx][m] = (r < NN) ? ab[(size_t)r * NN + kt + tx] : 0.f;
        }
#pragma unroll
        for (int i = 0; i < 3; i++) {
            int p = t + i * 256;               // [0,768)
            int kk = p / DD, d = p % DD;
            Bs[kk][d] = vb[(size_t)(kt + kk) * DD + d];
        }
        __syncthreads();
#pragma unroll
        for (int kk = 0; kk < 16; kk++) {
            float4 av = *(const float4*)&As[kk][ty * 4];
            float a4[4] = {av.x, av.y, av.z, av.w};
            float b0 = Bs[kk][tx * 3], b1 = Bs[kk][tx * 3 + 1], b2 = Bs[kk][tx * 3 + 2];
#pragma unroll
            for (int i = 0; i < 4; i++) {
                acc[i][0] = fmaf(a4[i], b0, acc[i][0]);
                acc[i][1] = fmaf(a4[i], b1, acc[i][1]);
                acc[i][2] = fmaf(a4[i], b2, acc[i][2]);
            }
        }
        __syncthreads();
    }
#pragma unroll
    for (int i = 0; i < 4; i++) {
        int r = row0 + ty * 4 + i;
        if (r >= NN) continue;
#pragma unroll
        for (int j = 0; j < 3; j++) {
            int d = tx * 3 + j;
            ws_o[((size_t)b * NN + r) * CC + h * DD + d] = acc[i][j];
        }
    }
}

// ---------------------------------------------------------------------------
// K6: out = ws_o @ Wproj^T + b_proj -> d_out out-section [B,N,C].
// grid (98, 12). NT GEMM like K1.
// ---------------------------------------------------------------------------
__global__ __launch_bounds__(256) void proj_kernel(
    const float* __restrict__ A, const float* __restrict__ W,
    const float* __restrict__ bias, float* __restrict__ out)
{
    const int row0 = blockIdx.x * 64, col0 = blockIdx.y * 64;
    __shared__ float As[16][68];
    __shared__ float Bs[16][68];
    const int t = threadIdx.x, tx = t & 15, ty = t >> 4;
    float acc[4][4] = {};

    for (int kt = 0; kt < CC; kt += 16) {
#pragma unroll
        for (int i = 0; i < 4; i++) {
            int m = ty + 16 * i;
            As[tx][m] = A[(size_t)(row0 + m) * CC + kt + tx];
            Bs[tx][m] = W[(size_t)(col0 + m) * CC + kt + tx];
        }
        __syncthreads();
#pragma unroll
        for (int kk = 0; kk < 16; kk++) {
            float4 av = *(const float4*)&As[kk][ty * 4];
            float4 bv = *(const float4*)&Bs[kk][tx * 4];
            float a4[4] = {av.x, av.y, av.z, av.w};
            float b4[4] = {bv.x, bv.y, bv.z, bv.w};
#pragma unroll
            for (int i = 0; i < 4; i++)
#pragma unroll
                for (int j = 0; j < 4; j++)
                    acc[i][j] = fmaf(a4[i], b4[j], acc[i][j]);
        }
        __syncthreads();
    }
#pragma unroll
    for (int i = 0; i < 4; i++) {
        int row = row0 + ty * 4 + i;
#pragma unroll
        for (int j = 0; j < 4; j++) {
            int c = col0 + tx * 4 + j;
            out[(size_t)row * CC + c] = acc[i][j] + bias[c];
        }
    }
}

extern "C" void kernel_launch(void* const* d_in, const int* in_sizes, int n_in,
                              void* d_out, int out_size, void* d_ws, size_t ws_size,
                              hipStream_t stream)
{
    const float* x      = (const float*)d_in[0];
    const float* Wq     = (const float*)d_in[1];
    const float* Wk     = (const float*)d_in[2];
    const float* Wv     = (const float*)d_in[3];
    const float* Wproj  = (const float*)d_in[4];
    const float* b_proj = (const float*)d_in[5];
    const float* W_pos  = (const float*)d_in[6];
    const float* b_pos  = (const float*)d_in[7];
    const float* gating = (const float*)d_in[8];

    float* out = (float*)d_out;
    float* ws  = (float*)d_ws;

    float* ws_q   = ws + WS_Q;
    float* ws_k   = ws + WS_K;
    float* ws_pos = ws + WS_POS;
    float* ws_o   = ws + WS_O;
    float* attn   = out + ATTN_OFF;
    float* vout   = out + V_OFF;

    hipLaunchKernelGGL(qkv_kernel, dim3(98, 36), dim3(256), 0, stream,
                       x, Wq, Wk, Wv, ws_q, ws_k, vout);
    hipLaunchKernelGGL(pos_kernel, dim3(HH * NN), dim3(256), 0, stream,
                       W_pos, b_pos, ws_pos);
    hipLaunchKernelGGL(score_kernel, dim3(13, 13, 128), dim3(256), 0, stream,
                       ws_q, ws_k, attn);
    hipLaunchKernelGGL(blend_kernel, dim3(BB * HH * NN), dim3(256), 0, stream,
                       ws_pos, gating, attn);
    hipLaunchKernelGGL(pv_kernel, dim3(13, 1, 128), dim3(256), 0, stream,
                       attn, vout, ws_o);
    hipLaunchKernelGGL(proj_kernel, dim3(98, 12), dim3(256), 0, stream,
                       ws_o, Wproj, b_proj, out);
}

// Round 2
// 814.881 us; speedup vs baseline: 1.7092x; 1.7092x over previous
//
#include <hip/hip_runtime.h>
#include <math.h>

#define BB 8
#define NN 784
#define CC 768
#define HH 16
#define DD 48
#define SCALE 0.14433756729740643f    // 48^-0.5

// d_out layout (floats): out [B,N,C] | attn [B,H,N,N] | v [B,H,N,D]
#define ATTN_OFF ((size_t)BB*NN*CC)                  // 4816896
#define V_OFF (ATTN_OFF + (size_t)BB*HH*NN*NN)       // 83492864

// workspace layout (shorts/bf16)
#define WS_XB ((size_t)0)                            // x bf16 [6272][768]
#define WS_WB ((size_t)4816896)                      // Wq|Wk|Wv|Wproj bf16, 4x[768][768]
#define WS_QB (WS_WB + (size_t)4*589824)             // q bf16 [B,H,N,D]
#define WS_KB (WS_QB + (size_t)4816896)              // k bf16 [B,H,N,D]
#define WS_VT (WS_KB + (size_t)4816896)              // v^T bf16 [B,H,D,N]
#define WS_OB (WS_VT + (size_t)4816896)              // attn@v bf16 [B,N,C]

using bf16x8 = __attribute__((ext_vector_type(8))) short;
using f32x4  = __attribute__((ext_vector_type(4))) float;

__device__ __forceinline__ short f2bf(float f) {
    union { float f; unsigned u; } uf; uf.f = f;
    unsigned u = uf.u;
    return (short)((u + 0x7FFFu + ((u >> 16) & 1u)) >> 16);   // RNE
}
__device__ __forceinline__ bf16x8 bzero() {
    bf16x8 z = {0,0,0,0,0,0,0,0};
    return z;
}
__device__ __forceinline__ bf16x8 cvt8(float4 a, float4 b) {
    bf16x8 r;
    r[0]=f2bf(a.x); r[1]=f2bf(a.y); r[2]=f2bf(a.z); r[3]=f2bf(a.w);
    r[4]=f2bf(b.x); r[5]=f2bf(b.y); r[6]=f2bf(b.z); r[7]=f2bf(b.w);
    return r;
}
#define MFMA16(a,b,c) __builtin_amdgcn_mfma_f32_16x16x32_bf16((a),(b),(c),0,0,0)

// ---------------------------------------------------------------------------
// K0: cast x and the 4 weights to bf16 in ws. 4 floats / thread.
// ---------------------------------------------------------------------------
__global__ __launch_bounds__(256) void cast_kernel(
    const float* __restrict__ x, const float* __restrict__ Wq,
    const float* __restrict__ Wk, const float* __restrict__ Wv,
    const float* __restrict__ Wp, short* __restrict__ xb, short* __restrict__ wb)
{
    int idx = blockIdx.x * 256 + threadIdx.x;   // group of 4 elements
    const float* src;
    short* dst;
    if (idx < 1204224) {                         // x: 4816896/4
        src = x + (size_t)idx * 4;
        dst = xb + (size_t)idx * 4;
    } else {
        int j = idx - 1204224;
        int sel = j / 147456;                    // 589824/4
        size_t off = (size_t)(j % 147456) * 4;
        const float* W = (sel == 0) ? Wq : (sel == 1) ? Wk : (sel == 2) ? Wv : Wp;
        src = W + off;
        dst = wb + (size_t)sel * 589824 + off;
    }
    float4 v = *(const float4*)src;
    union { short s[4]; uint2 u; } o;
    o.s[0] = f2bf(v.x); o.s[1] = f2bf(v.y); o.s[2] = f2bf(v.z); o.s[3] = f2bf(v.w);
    *(uint2*)dst = o.u;
}

// ---------------------------------------------------------------------------
// K1: QKV projection, bf16 MFMA NT GEMM. M=6272, N=3*768, K=768.
// grid (49, 18); block 256 = 4 waves in 2x2; wave tile 64x64 (4x4 mfma tiles).
// Fragments loaded directly from global (L2-resident weights).
// q,k -> bf16 ws [B,H,N,D]; v -> fp32 d_out [B,H,N,D] + bf16 ws V^T [B,H,D,N].
// ---------------------------------------------------------------------------
__global__ __launch_bounds__(256) void qkv_mfma(
    const short* __restrict__ xb, const short* __restrict__ wb,
    short* __restrict__ qb, short* __restrict__ kb,
    float* __restrict__ vo, short* __restrict__ vt)
{
    const int t = threadIdx.x, l = t & 63, ww = t >> 6;
    const int quad = l >> 4, lc = l & 15;
    const int m0 = blockIdx.x * 128 + (ww >> 1) * 64;
    const int bn = blockIdx.y;
    const int wsel = bn / 6;
    const int colbase = (bn % 6) * 128 + (ww & 1) * 64;
    const short* W = wb + (size_t)wsel * 589824;

    f32x4 acc[4][4] = {};
    const short* arow = xb + (size_t)(m0 + lc) * 768 + quad * 8;
    const short* brow = W  + (size_t)(colbase + lc) * 768 + quad * 8;

    for (int k0 = 0; k0 < 768; k0 += 32) {
        bf16x8 af[4], bf[4];
#pragma unroll
        for (int i = 0; i < 4; i++) af[i] = *(const bf16x8*)(arow + (size_t)i * 16 * 768 + k0);
#pragma unroll
        for (int j = 0; j < 4; j++) bf[j] = *(const bf16x8*)(brow + (size_t)j * 16 * 768 + k0);
#pragma unroll
        for (int i = 0; i < 4; i++)
#pragma unroll
            for (int j = 0; j < 4; j++)
                acc[i][j] = MFMA16(af[i], bf[j], acc[i][j]);
    }

#pragma unroll
    for (int i = 0; i < 4; i++) {
#pragma unroll
        for (int j = 0; j < 4; j++) {
            const int o = colbase + j * 16 + lc;
            const int h = o / DD, d = o % DD;
#pragma unroll
            for (int r = 0; r < 4; r++) {
                const int m = m0 + i * 16 + quad * 4 + r;
                const int b = m / NN, n = m % NN;
                const size_t bhnd = (((size_t)b * HH + h) * NN + n) * DD + d;
                const float v = acc[i][j][r];
                if (wsel == 0)      qb[bhnd] = f2bf(v);
                else if (wsel == 1) kb[bhnd] = f2bf(v);
                else {
                    vo[bhnd] = v;
                    vt[((size_t)(b * HH + h) * DD + d) * NN + n] = f2bf(v);
                }
            }
        }
    }
}

// ---------------------------------------------------------------------------
// K2: fused QK^T (bf16 MFMA) + patch softmax + on-the-fly positional softmax
// + gated blend + renorm -> final attn. Block owns a 16-row strip of one
// (b,h); grid (49, 128). LDS: 16x789 fp32 strip (~50.5 KB).
// ---------------------------------------------------------------------------
__global__ __launch_bounds__(256) void attn_fused(
    const short* __restrict__ qb, const short* __restrict__ kb,
    const float* __restrict__ W_pos, const float* __restrict__ b_pos,
    const float* __restrict__ gating, float* __restrict__ attn)
{
    const int t = threadIdx.x, l = t & 63, ww = t >> 6;
    const int quad = l >> 4, lc = l & 15;
    const int bh = blockIdx.y, h = bh & 15;
    const int row0 = blockIdx.x * 16;

    __shared__ float Sbuf[16][789];

    // ---- phase A: S strip = q(16x48) @ k^T, col-tiles split across waves
    const short* qrow = qb + ((size_t)bh * NN + row0 + lc) * DD;
    bf16x8 qf0 = *(const bf16x8*)(qrow + quad * 8);
    bf16x8 qf1 = (quad < 2) ? *(const bf16x8*)(qrow + 32 + quad * 8) : bzero();

    for (int ct = ww; ct < 49; ct += 4) {
        const int c0 = ct * 16;
        const short* krow = kb + ((size_t)bh * NN + c0 + lc) * DD;
        bf16x8 kf0 = *(const bf16x8*)(krow + quad * 8);
        bf16x8 kf1 = (quad < 2) ? *(const bf16x8*)(krow + 32 + quad * 8) : bzero();
        f32x4 cc = {0.f, 0.f, 0.f, 0.f};
        cc = MFMA16(qf0, kf0, cc);
        cc = MFMA16(qf1, kf1, cc);
#pragma unroll
        for (int r = 0; r < 4; r++)
            Sbuf[quad * 4 + r][c0 + lc] = cc[r] * SCALE;
    }

    // ---- positional softmax stats (independent of Sbuf; overlaps phase A)
    const int r = t >> 4, c = t & 15;
    const int nrow = row0 + r;
    const float w0 = W_pos[h * 3], w1 = W_pos[h * 3 + 1], w2 = W_pos[h * 3 + 2];
    const float bp = b_pos[h];
    const int nx = nrow % 28, ny = nrow / 28;

    float pm = -1e30f;
#pragma unroll 7
    for (int s = 0; s < 49; s++) {
        const int m = c + 16 * s;
        const float dx = (float)(m % 28 - nx), dy = (float)(m / 28 - ny);
        const float pl = fmaf(w2, dx * dx + dy * dy, fmaf(w0, dx, fmaf(w1, dy, bp)));
        pm = fmaxf(pm, pl);
    }
    pm = fmaxf(pm, __shfl_xor(pm, 1));
    pm = fmaxf(pm, __shfl_xor(pm, 2));
    pm = fmaxf(pm, __shfl_xor(pm, 4));
    pm = fmaxf(pm, __shfl_xor(pm, 8));
    float psum = 0.f;
#pragma unroll 7
    for (int s = 0; s < 49; s++) {
        const int m = c + 16 * s;
        const float dx = (float)(m % 28 - nx), dy = (float)(m / 28 - ny);
        const float pl = fmaf(w2, dx * dx + dy * dy, fmaf(w0, dx, fmaf(w1, dy, bp)));
        psum += __expf(pl - pm);
    }
    psum += __shfl_xor(psum, 1);
    psum += __shfl_xor(psum, 2);
    psum += __shfl_xor(psum, 4);
    psum += __shfl_xor(psum, 8);
    const float pinv = 1.f / psum;
    const float g = 1.f / (1.f + __expf(-gating[h]));

    __syncthreads();

    // ---- patch softmax over the strip (row fully owned by one 16-lane group)
    float sm = -1e30f;
#pragma unroll 7
    for (int s = 0; s < 49; s++) sm = fmaxf(sm, Sbuf[r][c + 16 * s]);
    sm = fmaxf(sm, __shfl_xor(sm, 1));
    sm = fmaxf(sm, __shfl_xor(sm, 2));
    sm = fmaxf(sm, __shfl_xor(sm, 4));
    sm = fmaxf(sm, __shfl_xor(sm, 8));
    float se = 0.f;
#pragma unroll 7
    for (int s = 0; s < 49; s++) {
        const float e = __expf(Sbuf[r][c + 16 * s] - sm);
        Sbuf[r][c + 16 * s] = e;
        se += e;
    }
    se += __shfl_xor(se, 1);
    se += __shfl_xor(se, 2);
    se += __shfl_xor(se, 4);
    se += __shfl_xor(se, 8);
    const float inv = 1.f / se;

    // ---- blend with positional softmax, accumulate row sum
    float sa = 0.f;
#pragma unroll 7
    for (int s = 0; s < 49; s++) {
        const int m = c + 16 * s;
        const float dx = (float)(m % 28 - nx), dy = (float)(m / 28 - ny);
        const float pl = fmaf(w2, dx * dx + dy * dy, fmaf(w0, dx, fmaf(w1, dy, bp)));
        const float a = (1.f - g) * Sbuf[r][m] * inv + g * __expf(pl - pm) * pinv;
        Sbuf[r][m] = a;
        sa += a;
    }
    sa += __shfl_xor(sa, 1);
    sa += __shfl_xor(sa, 2);
    sa += __shfl_xor(sa, 4);
    sa += __shfl_xor(sa, 8);
    const float inv2 = 1.f / sa;

    float* arow = attn + ((size_t)bh * NN + nrow) * NN;
#pragma unroll 7
    for (int s = 0; s < 49; s++) arow[c + 16 * s] = Sbuf[r][c + 16 * s] * inv2;
}

// ---------------------------------------------------------------------------
// K3: O = attn @ v via bf16 MFMA against V^T. grid (13, 128); wave = 16-row
// strip, 3 n-tiles (48 cols), K = 784 padded to 800. Output bf16 [B,N,C].
// ---------------------------------------------------------------------------
__global__ __launch_bounds__(256) void pv_mfma(
    const float* __restrict__ attn, const short* __restrict__ vt,
    short* __restrict__ ob)
{
    const int t = threadIdx.x, l = t & 63, ww = t >> 6;
    const int quad = l >> 4, lc = l & 15;
    const int bh = blockIdx.y, b = bh >> 4, h = bh & 15;
    const int r0 = blockIdx.x * 64 + ww * 16;
    if (r0 >= NN) return;

    const float* arow = attn + ((size_t)bh * NN + r0 + lc) * NN;
    const short* vbase = vt + (size_t)bh * DD * NN;

    f32x4 acc[3] = {};
    for (int kt = 0; kt < 25; kt++) {
        const int k0 = kt * 32 + quad * 8;
        bf16x8 af;
        if (k0 < NN) {
            float4 a0 = *(const float4*)(arow + k0);
            float4 a1 = *(const float4*)(arow + k0 + 4);
            af = cvt8(a0, a1);
        } else af = bzero();
#pragma unroll
        for (int j = 0; j < 3; j++) {
            bf16x8 bf = (k0 < NN)
                ? *(const bf16x8*)(vbase + (size_t)(j * 16 + lc) * NN + k0)
                : bzero();
            acc[j] = MFMA16(af, bf, acc[j]);
        }
    }
#pragma unroll
    for (int j = 0; j < 3; j++) {
        const int d = h * DD + j * 16 + lc;
#pragma unroll
        for (int r = 0; r < 4; r++) {
            const int row = r0 + quad * 4 + r;
            ob[((size_t)b * NN + row) * CC + d] = f2bf(acc[j][r]);
        }
    }
}

// ---------------------------------------------------------------------------
// K4: out = ob @ Wproj^T + bias, bf16 MFMA NT GEMM. M=6272, N=768, K=768.
// grid (49, 6); same structure as K1; fp32 output.
// ---------------------------------------------------------------------------
__global__ __launch_bounds__(256) void proj_mfma(
    const short* __restrict__ ob, const short* __restrict__ wb,
    const float* __restrict__ bias, float* __restrict__ out)
{
    const int t = threadIdx.x, l = t & 63, ww = t >> 6;
    const int quad = l >> 4, lc = l & 15;
    const int m0 = blockIdx.x * 128 + (ww >> 1) * 64;
    const int colbase = blockIdx.y * 128 + (ww & 1) * 64;
    const short* W = wb + (size_t)3 * 589824;   // Wproj

    f32x4 acc[4][4] = {};
    const short* arow = ob + (size_t)(m0 + lc) * 768 + quad * 8;
    const short* brow = W  + (size_t)(colbase + lc) * 768 + quad * 8;

    for (int k0 = 0; k0 < 768; k0 += 32) {
        bf16x8 af[4], bf[4];
#pragma unroll
        for (int i = 0; i < 4; i++) af[i] = *(const bf16x8*)(arow + (size_t)i * 16 * 768 + k0);
#pragma unroll
        for (int j = 0; j < 4; j++) bf[j] = *(const bf16x8*)(brow + (size_t)j * 16 * 768 + k0);
#pragma unroll
        for (int i = 0; i < 4; i++)
#pragma unroll
            for (int j = 0; j < 4; j++)
                acc[i][j] = MFMA16(af[i], bf[j], acc[i][j]);
    }

#pragma unroll
    for (int i = 0; i < 4; i++) {
#pragma unroll
        for (int j = 0; j < 4; j++) {
            const int o = colbase + j * 16 + lc;
            const float bo = bias[o];
#pragma unroll
            for (int r = 0; r < 4; r++) {
                const int m = m0 + i * 16 + quad * 4 + r;
                out[(size_t)m * CC + o] = acc[i][j][r] + bo;
            }
        }
    }
}

extern "C" void kernel_launch(void* const* d_in, const int* in_sizes, int n_in,
                              void* d_out, int out_size, void* d_ws, size_t ws_size,
                              hipStream_t stream)
{
    const float* x      = (const float*)d_in[0];
    const float* Wq     = (const float*)d_in[1];
    const float* Wk     = (const float*)d_in[2];
    const float* Wv     = (const float*)d_in[3];
    const float* Wproj  = (const float*)d_in[4];
    const float* b_proj = (const float*)d_in[5];
    const float* W_pos  = (const float*)d_in[6];
    const float* b_pos  = (const float*)d_in[7];
    const float* gating = (const float*)d_in[8];

    float* out  = (float*)d_out;
    short* ws   = (short*)d_ws;

    short* xb = ws + WS_XB;
    short* wb = ws + WS_WB;
    short* qb = ws + WS_QB;
    short* kb = ws + WS_KB;
    short* vt = ws + WS_VT;
    short* ob = ws + WS_OB;
    float* attn = out + ATTN_OFF;
    float* vout = out + V_OFF;

    hipLaunchKernelGGL(cast_kernel, dim3(7008), dim3(256), 0, stream,
                       x, Wq, Wk, Wv, Wproj, xb, wb);
    hipLaunchKernelGGL(qkv_mfma, dim3(49, 18), dim3(256), 0, stream,
                       xb, wb, qb, kb, vout, vt);
    hipLaunchKernelGGL(attn_fused, dim3(49, 128), dim3(256), 0, stream,
                       qb, kb, W_pos, b_pos, gating, attn);
    hipLaunchKernelGGL(pv_mfma, dim3(13, 128), dim3(256), 0, stream,
                       attn, vt, ob);
    hipLaunchKernelGGL(proj_mfma, dim3(49, 6), dim3(256), 0, stream,
                       ob, wb, b_proj, out);
}